// Round 6
// baseline (295.839 us; speedup 1.0000x reference)
//
#include <hip/hip_runtime.h>
#include <stdint.h>

#define N_BOX 128
#define HW    262144          // 512*512
#define SPLIT 16
#define CHUNK (HW / SPLIT)    // 16384 floats per mask-block
#define TOPK  64
#define NMASKBLK (N_BOX * SPLIT)   // 2048
typedef unsigned long long u64;
typedef float vf4 __attribute__((ext_vector_type(4)));   // native vec for nontemporal builtin

// ---------------- bitonic helpers (64-lane wave, u64 keys, descending) ----
__device__ __forceinline__ u64 sort64_desc(u64 v, int lane) {
#pragma unroll
  for (int size = 2; size <= 64; size <<= 1) {
#pragma unroll
    for (int stride = size >> 1; stride > 0; stride >>= 1) {
      const u64 o = __shfl_xor(v, stride);
      const bool blk   = ((lane & size) == 0);
      const bool lower = ((lane & stride) == 0);
      const u64 mx = (v > o) ? v : o;
      const u64 mn = (v > o) ? o : v;
      v = (blk == lower) ? mx : mn;
    }
  }
  return v;
}

// v, s: sorted desc. Returns top-64 of union, sorted desc (exact, distinct keys).
__device__ __forceinline__ u64 merge64_desc(u64 v, u64 s, int lane) {
  const u64 r = __shfl_xor(s, 63);        // reversed -> ascending
  v = (v > r) ? v : r;                    // elementwise max -> bitonic
#pragma unroll
  for (int stride = 32; stride > 0; stride >>= 1) {
    const u64 o = __shfl_xor(v, stride);
    const bool lower = ((lane & stride) == 0);
    const u64 mx = (v > o) ? v : o;
    const u64 mn = (v > o) ? o : v;
    v = lower ? mx : mn;
  }
  return v;
}

__device__ __forceinline__ float sigf(float x) { return 1.f / (1.f + expf(-x)); }

// ---------------- single fused kernel ----------------
// grid = 2049 x 1024 threads.
//   blocks 0..2047 : mask/depth partial sums -> part[]; last-ticket block
//                    additionally finalizes per-box scalars (out[0..383]).
//   block 2048     : IoU + exact top-64 (out[384..575]); independent of masks.
__global__ __launch_bounds__(1024) void k_fused(
    const float* __restrict__ boxes, const float* __restrict__ masks,
    const float* __restrict__ conf, const float* __restrict__ depth,
    float* __restrict__ part, unsigned* __restrict__ cnt,
    float* __restrict__ out) {
  const int t = threadIdx.x;
  const int lane = t & 63;
  const int w = t >> 6;

  // LDS (static; both paths' usage co-allocated, ~11 KB total)
  __shared__ float red[3][16];
  __shared__ int   isLast;
  __shared__ float X1[N_BOX], Y1[N_BOX], X2[N_BOX], Y2[N_BOX], A[N_BOX];
  __shared__ u64   wtop[16][TOPK];

  if (blockIdx.x < NMASKBLK) {
    // ================= mask partial path =================
    const int b = blockIdx.x;
    const int m = b >> 4;
    const int s = b & (SPLIT - 1);
    const vf4* mk = reinterpret_cast<const vf4*>(masks + (size_t)m * HW + (size_t)s * CHUNK);
    const vf4* dp = reinterpret_cast<const vf4*>(depth + (size_t)s * CHUNK);

    float c = 0.f, s1 = 0.f, s2 = 0.f;
#pragma unroll
    for (int j = 0; j < 4; ++j) {
      const int i = t + j * 1024;
      const vf4 mv = __builtin_nontemporal_load(&mk[i]);  // streaming, no reuse
      const vf4 dv = dp[i];                               // reused across blocks (L2)
      if (mv.x > 0.5f && dv.x > 1e-4f) { c += 1.f; s1 += dv.x; s2 += dv.x * dv.x; }
      if (mv.y > 0.5f && dv.y > 1e-4f) { c += 1.f; s1 += dv.y; s2 += dv.y * dv.y; }
      if (mv.z > 0.5f && dv.z > 1e-4f) { c += 1.f; s1 += dv.z; s2 += dv.z * dv.z; }
      if (mv.w > 0.5f && dv.w > 1e-4f) { c += 1.f; s1 += dv.w; s2 += dv.w * dv.w; }
    }
    for (int off = 32; off > 0; off >>= 1) {
      c  += __shfl_down(c,  off);
      s1 += __shfl_down(s1, off);
      s2 += __shfl_down(s2, off);
    }
    if (lane == 0) { red[0][w] = c; red[1][w] = s1; red[2][w] = s2; }
    __syncthreads();
    if (t == 0) {
      float C = 0.f, S1 = 0.f, S2 = 0.f;
#pragma unroll
      for (int k = 0; k < 16; ++k) { C += red[0][k]; S1 += red[1][k]; S2 += red[2][k]; }
      part[b * 3 + 0] = C;
      part[b * 3 + 1] = S1;
      part[b * 3 + 2] = S2;
      __threadfence();                         // release part[] device-wide
      const unsigned tk = atomicAdd(cnt, 1u);  // device-scope ticket
      isLast = (tk == NMASKBLK - 1) ? 1 : 0;
    }
    __syncthreads();

    if (isLast && t < N_BOX) {
      // ============ finalize (last block only; all part[] visible) ============
      __threadfence();                         // acquire
      volatile const float* vp = part;         // L1-bypass reads
      const int m2 = t;
      float C = 0.f, S1 = 0.f, S2 = 0.f;
#pragma unroll
      for (int s2i = 0; s2i < SPLIT; ++s2i) {
        C  += vp[(m2 * SPLIT + s2i) * 3 + 0];
        S1 += vp[(m2 * SPLIT + s2i) * 3 + 1];
        S2 += vp[(m2 * SPLIT + s2i) * 3 + 2];
      }
      const float cntf = fmaxf(C, 1.f);
      const float mean = S1 / cntf;
      float var = S2 / cntf - mean * mean;
      var = (C > 0.f) ? fmaxf(var, 0.f) : 0.f;

      const float x1 = boxes[m2 * 4 + 0], y1 = boxes[m2 * 4 + 1];
      const float x2 = boxes[m2 * 4 + 2], y2 = boxes[m2 * 4 + 3];
      const float bw = fmaxf(x2 - x1, 0.f);
      const float bh = fmaxf(y2 - y1, 0.f);
      const float area = fminf(fmaxf(bw * bh, 0.f), 1.f);
      const float cf = conf[m2];
      const float tall = fminf(fmaxf(bh / (bw + 1e-6f), 0.f), 10.f);
      const float thin = sigf((tall - 1.2f) * 2.f);
      const float unst = fminf(fmaxf(0.35f * thin + 0.35f * sigf(var * 6.f) + 0.3f * (1.f - cf), 0.f), 1.f);
      const float slip = fminf(fmaxf(0.45f * sigf(var * 8.f) + 0.25f * (1.f - cf) + 0.3f * sigf((area - 0.05f) * 3.f), 0.f), 1.f);
      out[m2]             = unst;
      out[N_BOX + m2]     = slip;
      out[2 * N_BOX + m2] = fminf(fmaxf(1.f - unst, 0.f), 1.f);
    }
  } else {
    // ================= top-64 path (independent of masks) =================
    if (t < N_BOX) {
      const float x1 = boxes[t * 4 + 0], y1 = boxes[t * 4 + 1];
      const float x2 = boxes[t * 4 + 2], y2 = boxes[t * 4 + 3];
      X1[t] = x1; Y1[t] = y1; X2[t] = x2; Y2[t] = y2;
      A[t] = fmaxf(x2 - x1, 0.f) * fmaxf(y2 - y1, 0.f);
    }
    __syncthreads();

    u64 v = 0ULL;
#pragma unroll
    for (int b = 0; b < 16; ++b) {
      const int e = w * 1024 + b * 64 + lane;
      const int i = e >> 7, jj = e & 127;
      const float xx1 = fmaxf(X1[i], X1[jj]);
      const float yy1 = fmaxf(Y1[i], Y1[jj]);
      const float xx2 = fminf(X2[i], X2[jj]);
      const float yy2 = fminf(Y2[i], Y2[jj]);
      const float inter = fmaxf(xx2 - xx1, 0.f) * fmaxf(yy2 - yy1, 0.f);
      const float uni = A[i] + A[jj] - inter;
      float iou = inter / (uni + 1e-6f);
      if (i == jj) iou = 0.f;
      const float mval = (iou > 0.02f) ? iou : -1.0f;
      uint32_t u = __float_as_uint(mval);
      u = (u & 0x80000000u) ? ~u : (u | 0x80000000u);   // monotonic float->u32
      const u64 key = ((u64)u << 32) | (u64)(0xFFFFFFFFu - (uint32_t)e);

      if (b == 0) {
        v = sort64_desc(key, lane);
      } else {
        const u64 cut = __shfl(v, 63);      // current 64th-largest
        if (__any(key > cut)) {
          const u64 s = sort64_desc(key, lane);
          v = merge64_desc(v, s, lane);
        }
      }
    }
    wtop[w][lane] = v;
    __syncthreads();

    if (w == 0) {
#pragma unroll
      for (int ww = 1; ww < 16; ++ww)
        v = merge64_desc(v, wtop[ww][lane], lane);
      const uint32_t mh = (uint32_t)(v >> 32);
      const uint32_t u  = (mh & 0x80000000u) ? (mh ^ 0x80000000u) : ~mh;
      const float val   = __uint_as_float(u);
      const uint32_t e  = 0xFFFFFFFFu - (uint32_t)(v & 0xFFFFFFFFu);
      const bool valid  = (val > 0.02f);
      out[3 * N_BOX + 2 * lane + 0] = valid ? (float)(e >> 7)  : 0.f;
      out[3 * N_BOX + 2 * lane + 1] = valid ? (float)(e & 127) : 0.f;
      out[3 * N_BOX + 2 * TOPK + lane] = valid ? fminf(fmaxf(val * 5.f, 0.f), 1.f) : 0.f;
    }
  }
}

extern "C" void kernel_launch(void* const* d_in, const int* in_sizes, int n_in,
                              void* d_out, int out_size, void* d_ws, size_t ws_size,
                              hipStream_t stream) {
  const float* boxes = (const float*)d_in[0];
  const float* masks = (const float*)d_in[1];
  const float* conf  = (const float*)d_in[2];
  const float* depth = (const float*)d_in[3];
  float* out  = (float*)d_out;
  float* part = (float*)d_ws;                          // 2048*3 floats = 24 KB
  unsigned* cnt = (unsigned*)((char*)d_ws + 24576);    // 4-byte ticket counter

  (void)hipMemsetAsync(cnt, 0, 4, stream);             // zero the ticket
  hipLaunchKernelGGL(k_fused, dim3(NMASKBLK + 1), dim3(1024), 0, stream,
                     boxes, masks, conf, depth, part, cnt, out);
}

// Round 8
// 209.491 us; speedup vs baseline: 1.4122x; 1.4122x over previous
//
#include <hip/hip_runtime.h>
#include <stdint.h>

#define N_BOX 128
#define HW    262144          // 512*512
#define SPLIT 16
#define CHUNK (HW / SPLIT)    // 16384 floats per block
#define TOPK  64
typedef unsigned long long u64;

// ---------------- Kernel V: per-(mask, split) partial sums (R2-proven) ----
__global__ __launch_bounds__(256) void k_mask_partial(
    const float* __restrict__ masks, const float* __restrict__ depth,
    float* __restrict__ part) {
  const int b = blockIdx.x;
  const int m = b >> 4;             // / SPLIT
  const int s = b & (SPLIT - 1);
  const float4* mk = reinterpret_cast<const float4*>(masks + (size_t)m * HW + (size_t)s * CHUNK);
  const float4* dp = reinterpret_cast<const float4*>(depth + (size_t)s * CHUNK);
  const int t = threadIdx.x;

  float c = 0.f, s1 = 0.f, s2 = 0.f;
#pragma unroll
  for (int j = 0; j < 16; ++j) {
    const int i = t + j * 256;
    float4 mv = mk[i];
    float4 dv = dp[i];
    if (mv.x > 0.5f && dv.x > 1e-4f) { c += 1.f; s1 += dv.x; s2 += dv.x * dv.x; }
    if (mv.y > 0.5f && dv.y > 1e-4f) { c += 1.f; s1 += dv.y; s2 += dv.y * dv.y; }
    if (mv.z > 0.5f && dv.z > 1e-4f) { c += 1.f; s1 += dv.z; s2 += dv.z * dv.z; }
    if (mv.w > 0.5f && dv.w > 1e-4f) { c += 1.f; s1 += dv.w; s2 += dv.w * dv.w; }
  }
  for (int off = 32; off > 0; off >>= 1) {
    c  += __shfl_down(c,  off);
    s1 += __shfl_down(s1, off);
    s2 += __shfl_down(s2, off);
  }
  __shared__ float red[3][4];
  const int wid = t >> 6, lane = t & 63;
  if (lane == 0) { red[0][wid] = c; red[1][wid] = s1; red[2][wid] = s2; }
  __syncthreads();
  if (t == 0) {
    part[b * 3 + 0] = red[0][0] + red[0][1] + red[0][2] + red[0][3];
    part[b * 3 + 1] = red[1][0] + red[1][1] + red[1][2] + red[1][3];
    part[b * 3 + 2] = red[2][0] + red[2][1] + red[2][2] + red[2][3];
  }
}

// ---------------- bitonic helpers (64-lane wave, u64 keys, descending) ----
__device__ __forceinline__ u64 sort64_desc(u64 v, int lane) {
#pragma unroll
  for (int size = 2; size <= 64; size <<= 1) {
#pragma unroll
    for (int stride = size >> 1; stride > 0; stride >>= 1) {
      const u64 o = __shfl_xor(v, stride);
      const bool blk   = ((lane & size) == 0);
      const bool lower = ((lane & stride) == 0);
      const u64 mx = (v > o) ? v : o;
      const u64 mn = (v > o) ? o : v;
      v = (blk == lower) ? mx : mn;
    }
  }
  return v;
}

// v, s: sorted desc. Returns top-64 of union, sorted desc.
__device__ __forceinline__ u64 merge64_desc(u64 v, u64 s, int lane) {
  const u64 r = __shfl_xor(s, 63);        // reversed -> ascending
  v = (v > r) ? v : r;                    // elementwise max -> bitonic
#pragma unroll
  for (int stride = 32; stride > 0; stride >>= 1) {
    const u64 o = __shfl_xor(v, stride);
    const bool lower = ((lane & stride) == 0);
    const u64 mx = (v > o) ? v : o;
    const u64 mn = (v > o) ? o : v;
    v = lower ? mx : mn;
  }
  return v;
}

__device__ __forceinline__ float sigf(float x) { return 1.f / (1.f + expf(-x)); }

// ---------------- Kernel T: IoU + exact top-64 + fused finalize ----------
// 16 waves. Per wave: seed run = sorted batch 0; batches 1..15 COMPACT
// candidates (iou>0.02) into a 64-deep LDS buffer (ballot+popc prefix),
// sort+merge only on overflow / at end. Wave 0 additionally full-merges
// batch 1, so entries e in [0,128) are always fully covered -> the -1.0
// fillers (needed only when total candidates < 64, and then all within
// the first 128 flat indices) are exact. 0-key pads decode to invalid and
// can never reach the final top-64 (>=1024 real keys in the union).
__global__ __launch_bounds__(1024) void k_topk_fin(
    const float* __restrict__ boxes, const float* __restrict__ conf,
    const float* __restrict__ part, float* __restrict__ out) {
  __shared__ float X1[N_BOX], Y1[N_BOX], X2[N_BOX], Y2[N_BOX], A[N_BOX];
  __shared__ u64 wtop[16][TOPK];
  __shared__ u64 wcand[16][TOPK];

  const int t = threadIdx.x;
  const int lane = t & 63;
  const int w = t >> 6;

  if (t < N_BOX) {
    const float x1 = boxes[t * 4 + 0], y1 = boxes[t * 4 + 1];
    const float x2 = boxes[t * 4 + 2], y2 = boxes[t * 4 + 3];
    X1[t] = x1; Y1[t] = y1; X2[t] = x2; Y2[t] = y2;
    A[t] = fmaxf(x2 - x1, 0.f) * fmaxf(y2 - y1, 0.f);
  }
  __syncthreads();

  u64 run = 0ULL;
  int nbuf = 0;                         // wave-uniform candidate count
#pragma unroll
  for (int b = 0; b < 16; ++b) {
    const int e = w * 1024 + b * 64 + lane;
    const int i = e >> 7, jj = e & 127;
    const float xx1 = fmaxf(X1[i], X1[jj]);
    const float yy1 = fmaxf(Y1[i], Y1[jj]);
    const float xx2 = fminf(X2[i], X2[jj]);
    const float yy2 = fminf(Y2[i], Y2[jj]);
    const float inter = fmaxf(xx2 - xx1, 0.f) * fmaxf(yy2 - yy1, 0.f);
    const float uni = A[i] + A[jj] - inter;
    float iou = inter / (uni + 1e-6f);
    if (i == jj) iou = 0.f;
    const bool cand = (iou > 0.02f);
    const float mval = cand ? iou : -1.0f;
    uint32_t u = __float_as_uint(mval);
    u = (u & 0x80000000u) ? ~u : (u | 0x80000000u);   // monotonic float->u32
    const u64 key = ((u64)u << 32) | (u64)(0xFFFFFFFFu - (uint32_t)e);

    if (b == 0) {
      run = sort64_desc(key, lane);                    // seed: full batch 0
    } else {
      const u64 mask = __ballot(cand);
      const int nc = __popcll(mask);
      if ((w == 0 && b == 1) || (nbuf + nc > TOPK)) {
        // full-batch merge (covers e in [64,128) for wave 0; overflow path)
        run = merge64_desc(run, sort64_desc(key, lane), lane);
      } else if (nc) {
        const int pos = nbuf + __popcll(mask & ((1ULL << lane) - 1ULL));
        if (cand) wcand[w][pos] = key;
        nbuf += nc;
      }
    }
  }
  if (nbuf > 0) {                       // flush buffered candidates
    const u64 k = (lane < nbuf) ? wcand[w][lane] : 0ULL;   // 0-pad = invalid
    run = merge64_desc(run, sort64_desc(k, lane), lane);
  }
  wtop[w][lane] = run;
  __syncthreads();

  // 4-level tree merge of the 16 sorted lists (read-regs / barrier / write)
  for (int n = 8; n >= 1; n >>= 1) {
    u64 a = 0ULL, bb = 0ULL;
    if (w < n) { a = wtop[2 * w][lane]; bb = wtop[2 * w + 1][lane]; }
    __syncthreads();
    if (w < n) wtop[w][lane] = merge64_desc(a, bb, lane);
    __syncthreads();
  }

  if (w == 0) {
    const u64 v = wtop[0][lane];
    const uint32_t mh = (uint32_t)(v >> 32);
    const uint32_t u  = (mh & 0x80000000u) ? (mh ^ 0x80000000u) : ~mh;
    const float val   = __uint_as_float(u);
    const uint32_t e  = 0xFFFFFFFFu - (uint32_t)(v & 0xFFFFFFFFu);
    const bool valid  = (val > 0.02f);
    out[3 * N_BOX + 2 * lane + 0] = valid ? (float)(e >> 7)  : 0.f;
    out[3 * N_BOX + 2 * lane + 1] = valid ? (float)(e & 127) : 0.f;
    out[3 * N_BOX + 2 * TOPK + lane] = valid ? fminf(fmaxf(val * 5.f, 0.f), 1.f) : 0.f;
  } else if (w == 2 || w == 3) {
    // fused finalize: per-box scalars (part[] from prior kernel, same stream)
    const int m = t - 128;
    float C = 0.f, S1 = 0.f, S2 = 0.f;
#pragma unroll
    for (int s = 0; s < SPLIT; ++s) {
      C  += part[(m * SPLIT + s) * 3 + 0];
      S1 += part[(m * SPLIT + s) * 3 + 1];
      S2 += part[(m * SPLIT + s) * 3 + 2];
    }
    const float cntf = fmaxf(C, 1.f);
    const float mean = S1 / cntf;
    float var = S2 / cntf - mean * mean;
    var = (C > 0.f) ? fmaxf(var, 0.f) : 0.f;

    const float x1 = X1[m], y1 = Y1[m], x2 = X2[m], y2 = Y2[m];
    const float bw = fmaxf(x2 - x1, 0.f);
    const float bh = fmaxf(y2 - y1, 0.f);
    const float area = fminf(fmaxf(bw * bh, 0.f), 1.f);
    const float cf = conf[m];
    const float tall = fminf(fmaxf(bh / (bw + 1e-6f), 0.f), 10.f);
    const float thin = sigf((tall - 1.2f) * 2.f);
    const float unst = fminf(fmaxf(0.35f * thin + 0.35f * sigf(var * 6.f) + 0.3f * (1.f - cf), 0.f), 1.f);
    const float slip = fminf(fmaxf(0.45f * sigf(var * 8.f) + 0.25f * (1.f - cf) + 0.3f * sigf((area - 0.05f) * 3.f), 0.f), 1.f);
    out[m]             = unst;
    out[N_BOX + m]     = slip;
    out[2 * N_BOX + m] = fminf(fmaxf(1.f - unst, 0.f), 1.f);
  }
}

extern "C" void kernel_launch(void* const* d_in, const int* in_sizes, int n_in,
                              void* d_out, int out_size, void* d_ws, size_t ws_size,
                              hipStream_t stream) {
  const float* boxes = (const float*)d_in[0];
  const float* masks = (const float*)d_in[1];
  const float* conf  = (const float*)d_in[2];
  const float* depth = (const float*)d_in[3];
  float* out  = (float*)d_out;
  float* part = (float*)d_ws;   // 2048*3 floats = 24 KB, fully written each call

  hipLaunchKernelGGL(k_mask_partial, dim3(N_BOX * SPLIT), dim3(256), 0, stream,
                     masks, depth, part);
  hipLaunchKernelGGL(k_topk_fin, dim3(1), dim3(1024), 0, stream,
                     boxes, conf, part, out);
}

// Round 9
// 195.462 us; speedup vs baseline: 1.5135x; 1.0718x over previous
//
#include <hip/hip_runtime.h>
#include <stdint.h>

#define N_BOX 128
#define HW    262144          // 512*512
#define SPLIT 16
#define CHUNK (HW / SPLIT)    // 16384 floats per mask-block
#define TOPK  64
#define NMASKBLK (N_BOX * SPLIT)   // 2048
typedef unsigned long long u64;

// ---------------- bitonic helpers (64-lane wave, u64 keys, descending) ----
__device__ __forceinline__ u64 sort64_desc(u64 v, int lane) {
#pragma unroll
  for (int size = 2; size <= 64; size <<= 1) {
#pragma unroll
    for (int stride = size >> 1; stride > 0; stride >>= 1) {
      const u64 o = __shfl_xor(v, stride);
      const bool blk   = ((lane & size) == 0);
      const bool lower = ((lane & stride) == 0);
      const u64 mx = (v > o) ? v : o;
      const u64 mn = (v > o) ? o : v;
      v = (blk == lower) ? mx : mn;
    }
  }
  return v;
}

// v, s: sorted desc. Returns top-64 of union, sorted desc.
__device__ __forceinline__ u64 merge64_desc(u64 v, u64 s, int lane) {
  const u64 r = __shfl_xor(s, 63);        // reversed -> ascending
  v = (v > r) ? v : r;                    // elementwise max -> bitonic
#pragma unroll
  for (int stride = 32; stride > 0; stride >>= 1) {
    const u64 o = __shfl_xor(v, stride);
    const bool lower = ((lane & stride) == 0);
    const u64 mx = (v > o) ? v : o;
    const u64 mn = (v > o) ? o : v;
    v = lower ? mx : mn;
  }
  return v;
}

__device__ __forceinline__ float sigf(float x) { return 1.f / (1.f + expf(-x)); }

// ---------------- fused kernel: mask scan + concurrent top-64 ----------
// grid = 2049 x 1024. Block 0 (scheduled first) = IoU top-64 via candidate
// compaction (R8-proven, out[384..575], depends only on boxes). Blocks
// 1..2048 = mask/depth partial sums -> part[] (R2/R6-proven math). No
// ticket, no fence -- the R6 cross-XCD atomic serialization is gone.
__global__ __launch_bounds__(1024) void k_fused(
    const float* __restrict__ boxes, const float* __restrict__ masks,
    const float* __restrict__ depth, float* __restrict__ part,
    float* __restrict__ out) {
  __shared__ float red[3][16];
  __shared__ float X1[N_BOX], Y1[N_BOX], X2[N_BOX], Y2[N_BOX], A[N_BOX];
  __shared__ u64 wtop[16][TOPK];
  __shared__ u64 wcand[16][TOPK];

  const int t = threadIdx.x;
  const int lane = t & 63;
  const int w = t >> 6;

  if (blockIdx.x != 0) {
    // ================= mask partial path (1024 thr, 4 x float4) =========
    const int b = blockIdx.x - 1;
    const int m = b >> 4;
    const int s = b & (SPLIT - 1);
    const float4* mk = reinterpret_cast<const float4*>(masks + (size_t)m * HW + (size_t)s * CHUNK);
    const float4* dp = reinterpret_cast<const float4*>(depth + (size_t)s * CHUNK);

    float c = 0.f, s1 = 0.f, s2 = 0.f;
#pragma unroll
    for (int j = 0; j < 4; ++j) {
      const int i = t + j * 1024;
      const float4 mv = mk[i];
      const float4 dv = dp[i];
      if (mv.x > 0.5f && dv.x > 1e-4f) { c += 1.f; s1 += dv.x; s2 += dv.x * dv.x; }
      if (mv.y > 0.5f && dv.y > 1e-4f) { c += 1.f; s1 += dv.y; s2 += dv.y * dv.y; }
      if (mv.z > 0.5f && dv.z > 1e-4f) { c += 1.f; s1 += dv.z; s2 += dv.z * dv.z; }
      if (mv.w > 0.5f && dv.w > 1e-4f) { c += 1.f; s1 += dv.w; s2 += dv.w * dv.w; }
    }
    for (int off = 32; off > 0; off >>= 1) {
      c  += __shfl_down(c,  off);
      s1 += __shfl_down(s1, off);
      s2 += __shfl_down(s2, off);
    }
    if (lane == 0) { red[0][w] = c; red[1][w] = s1; red[2][w] = s2; }
    __syncthreads();
    if (t == 0) {
      float C = 0.f, S1 = 0.f, S2 = 0.f;
#pragma unroll
      for (int k = 0; k < 16; ++k) { C += red[0][k]; S1 += red[1][k]; S2 += red[2][k]; }
      part[b * 3 + 0] = C;
      part[b * 3 + 1] = S1;
      part[b * 3 + 2] = S2;
    }
    return;
  }

  // ================= top-64 path (block 0; R8-proven compaction) =========
  if (t < N_BOX) {
    const float x1 = boxes[t * 4 + 0], y1 = boxes[t * 4 + 1];
    const float x2 = boxes[t * 4 + 2], y2 = boxes[t * 4 + 3];
    X1[t] = x1; Y1[t] = y1; X2[t] = x2; Y2[t] = y2;
    A[t] = fmaxf(x2 - x1, 0.f) * fmaxf(y2 - y1, 0.f);
  }
  __syncthreads();

  u64 run = 0ULL;
  int nbuf = 0;                         // wave-uniform candidate count
#pragma unroll
  for (int b = 0; b < 16; ++b) {
    const int e = w * 1024 + b * 64 + lane;
    const int i = e >> 7, jj = e & 127;
    const float xx1 = fmaxf(X1[i], X1[jj]);
    const float yy1 = fmaxf(Y1[i], Y1[jj]);
    const float xx2 = fminf(X2[i], X2[jj]);
    const float yy2 = fminf(Y2[i], Y2[jj]);
    const float inter = fmaxf(xx2 - xx1, 0.f) * fmaxf(yy2 - yy1, 0.f);
    const float uni = A[i] + A[jj] - inter;
    float iou = inter / (uni + 1e-6f);
    if (i == jj) iou = 0.f;
    const bool cand = (iou > 0.02f);
    const float mval = cand ? iou : -1.0f;
    uint32_t u = __float_as_uint(mval);
    u = (u & 0x80000000u) ? ~u : (u | 0x80000000u);   // monotonic float->u32
    const u64 key = ((u64)u << 32) | (u64)(0xFFFFFFFFu - (uint32_t)e);

    if (b == 0) {
      run = sort64_desc(key, lane);                    // seed: full batch 0
    } else {
      const u64 mask = __ballot(cand);
      const int nc = __popcll(mask);
      if ((w == 0 && b == 1) || (nbuf + nc > TOPK)) {
        // full-batch merge (covers e in [64,128) for wave 0; overflow path)
        run = merge64_desc(run, sort64_desc(key, lane), lane);
      } else if (nc) {
        const int pos = nbuf + __popcll(mask & ((1ULL << lane) - 1ULL));
        if (cand) wcand[w][pos] = key;
        nbuf += nc;
      }
    }
  }
  if (nbuf > 0) {                       // flush buffered candidates
    const u64 k = (lane < nbuf) ? wcand[w][lane] : 0ULL;   // 0-pad = invalid
    run = merge64_desc(run, sort64_desc(k, lane), lane);
  }
  wtop[w][lane] = run;
  __syncthreads();

  // 4-level tree merge of the 16 sorted lists
  for (int n = 8; n >= 1; n >>= 1) {
    u64 a = 0ULL, bb = 0ULL;
    if (w < n) { a = wtop[2 * w][lane]; bb = wtop[2 * w + 1][lane]; }
    __syncthreads();
    if (w < n) wtop[w][lane] = merge64_desc(a, bb, lane);
    __syncthreads();
  }

  if (w == 0) {
    const u64 v = wtop[0][lane];
    const uint32_t mh = (uint32_t)(v >> 32);
    const uint32_t u  = (mh & 0x80000000u) ? (mh ^ 0x80000000u) : ~mh;
    const float val   = __uint_as_float(u);
    const uint32_t e  = 0xFFFFFFFFu - (uint32_t)(v & 0xFFFFFFFFu);
    const bool valid  = (val > 0.02f);
    out[3 * N_BOX + 2 * lane + 0] = valid ? (float)(e >> 7)  : 0.f;
    out[3 * N_BOX + 2 * lane + 1] = valid ? (float)(e & 127) : 0.f;
    out[3 * N_BOX + 2 * TOPK + lane] = valid ? fminf(fmaxf(val * 5.f, 0.f), 1.f) : 0.f;
  }
}

// ---------------- finalize: per-box scalars (needs all part[]) ----------
__global__ __launch_bounds__(128) void k_finalize(
    const float* __restrict__ boxes, const float* __restrict__ conf,
    const float* __restrict__ part, float* __restrict__ out) {
  const int m = threadIdx.x;
  float C = 0.f, S1 = 0.f, S2 = 0.f;
#pragma unroll
  for (int s = 0; s < SPLIT; ++s) {
    C  += part[(m * SPLIT + s) * 3 + 0];
    S1 += part[(m * SPLIT + s) * 3 + 1];
    S2 += part[(m * SPLIT + s) * 3 + 2];
  }
  const float cntf = fmaxf(C, 1.f);
  const float mean = S1 / cntf;
  float var = S2 / cntf - mean * mean;
  var = (C > 0.f) ? fmaxf(var, 0.f) : 0.f;

  const float x1 = boxes[m * 4 + 0], y1 = boxes[m * 4 + 1];
  const float x2 = boxes[m * 4 + 2], y2 = boxes[m * 4 + 3];
  const float bw = fmaxf(x2 - x1, 0.f);
  const float bh = fmaxf(y2 - y1, 0.f);
  const float area = fminf(fmaxf(bw * bh, 0.f), 1.f);
  const float cf = conf[m];
  const float tall = fminf(fmaxf(bh / (bw + 1e-6f), 0.f), 10.f);
  const float thin = sigf((tall - 1.2f) * 2.f);
  const float unst = fminf(fmaxf(0.35f * thin + 0.35f * sigf(var * 6.f) + 0.3f * (1.f - cf), 0.f), 1.f);
  const float slip = fminf(fmaxf(0.45f * sigf(var * 8.f) + 0.25f * (1.f - cf) + 0.3f * sigf((area - 0.05f) * 3.f), 0.f), 1.f);
  out[m]             = unst;
  out[N_BOX + m]     = slip;
  out[2 * N_BOX + m] = fminf(fmaxf(1.f - unst, 0.f), 1.f);
}

extern "C" void kernel_launch(void* const* d_in, const int* in_sizes, int n_in,
                              void* d_out, int out_size, void* d_ws, size_t ws_size,
                              hipStream_t stream) {
  const float* boxes = (const float*)d_in[0];
  const float* masks = (const float*)d_in[1];
  const float* conf  = (const float*)d_in[2];
  const float* depth = (const float*)d_in[3];
  float* out  = (float*)d_out;
  float* part = (float*)d_ws;   // 2048*3 floats = 24 KB, fully written each call

  hipLaunchKernelGGL(k_fused, dim3(NMASKBLK + 1), dim3(1024), 0, stream,
                     boxes, masks, depth, part, out);
  hipLaunchKernelGGL(k_finalize, dim3(1), dim3(128), 0, stream,
                     boxes, conf, part, out);
}